// Round 4
// baseline (200.142 us; speedup 1.0000x reference)
//
#include <hip/hip_runtime.h>
#include <hip/hip_bf16.h>

typedef __attribute__((ext_vector_type(8))) short short8;
typedef __attribute__((ext_vector_type(4))) float f32x4;

#define NPERB   110592          // 48^3 points per batch
#define NTOTAL  221184          // B=2
#define HSTRIDE 72              // LDS row stride (bf16 elems) for h-transpose

// Pack two floats to packed bf16 (RNE). Scalar casts fuse to v_cvt_pk_bf16_f32
// (m240: do NOT hand-write the asm; the compiler handles it).
// NOTE: __hip_bfloat162 is not trivially copyable -> memcpy, not bit_cast.
static __device__ __forceinline__ unsigned pack_bf2(float a, float b) {
    __hip_bfloat162 t = __float22bfloat162_rn(float2{a, b});
    unsigned u;
    __builtin_memcpy(&u, &t, sizeof(u));
    return u;
}

// Load 8 consecutive fp32 from a W row, convert to a bf16 MFMA A-fragment.
static __device__ __forceinline__ short8 make_wfrag(const float* __restrict__ row) {
    const float4 a = *reinterpret_cast<const float4*>(row);
    const float4 b = *reinterpret_cast<const float4*>(row + 4);
    uint4 u;
    u.x = pack_bf2(a.x, a.y);
    u.y = pack_bf2(a.z, a.w);
    u.z = pack_bf2(b.x, b.y);
    u.w = pack_bf2(b.z, b.w);
    short8 r;
    __builtin_memcpy(&r, &u, sizeof(r));
    return r;
}

__global__ __launch_bounds__(256) void liquid_ode_kernel(
    const float* __restrict__ coords,
    const float* __restrict__ Wh,   const float* __restrict__ Uh,   const float* __restrict__ bh,
    const float* __restrict__ Wtau, const float* __restrict__ Utau, const float* __restrict__ btau,
    const float* __restrict__ Wout, const float* __restrict__ bout,
    float* __restrict__ out)
{
    // Only the per-wave h-transpose buffer lives in LDS now (9216 B/block).
    __shared__ __align__(16) unsigned short hT[4][16 * HSTRIDE];

    const int tid  = threadIdx.x;
    const int wid  = tid >> 6;
    const int lane = tid & 63;
    const int p    = lane & 15;   // point within wave tile (= MFMA col / A-frag row)
    const int G    = lane >> 4;   // lane group

    const int wave_global = blockIdx.x * 4 + wid;
    const int nf = wave_global * 16 + p;          // flat point over B*N
    const int b  = nf / NPERB;
    const int n  = nf - b * NPERB;

    const float cx = coords[nf * 3 + 0];
    const float cy = coords[nf * 3 + 1];
    const float cz = coords[nf * 3 + 2];

    // ---- W fragments: loop-invariant, straight from global into registers ----
    // A-frag for 16x16x32: lane (G,p) holds W[16mt+p][8G + j + 32kt], j=0..7.
    short8 wt_frag[4][2], wh_frag[4][2];
    #pragma unroll
    for (int mt = 0; mt < 4; ++mt) {
        const int rowoff = (16 * mt + p) * 64 + 8 * G;
        #pragma unroll
        for (int kt = 0; kt < 2; ++kt) {
            wt_frag[mt][kt] = make_wfrag(Wtau + rowoff + 32 * kt);
            wh_frag[mt][kt] = make_wfrag(Wh   + rowoff + 32 * kt);
        }
    }

    // D-layout per-lane state: element (mt, r) <-> g = 16*mt + 4*G + r, point p
    f32x4 ut[4], uh[4];
    float hs[4][4];
    #pragma unroll
    for (int mt = 0; mt < 4; ++mt) {
        #pragma unroll
        for (int r = 0; r < 4; ++r) {
            const int g = 16 * mt + 4 * G + r;
            ut[mt][r] = btau[g] + Utau[g*3+0]*cx + Utau[g*3+1]*cy + Utau[g*3+2]*cz;
            uh[mt][r] = bh[g]   + Uh[g*3+0]*cx   + Uh[g*3+1]*cy   + Uh[g*3+2]*cz;
            hs[mt][r] = 0.0f;
        }
    }

    unsigned short* myhT = hT[wid];

    #pragma unroll 1
    for (int s = 0; s < 8; ++s) {
        // ---- write h (packed bf16) into wave-local transpose buffer [p][g] ----
        #pragma unroll
        for (int mt = 0; mt < 4; ++mt) {
            uint2 v;
            v.x = pack_bf2(hs[mt][0], hs[mt][1]);
            v.y = pack_bf2(hs[mt][2], hs[mt][3]);
            *reinterpret_cast<uint2*>(&myhT[p * HSTRIDE + 16 * mt + 4 * G]) = v;
        }
        // ---- read MFMA B-fragments: lane holds h[k = 32*kt + 8*G + j][p] ----
        // (same-wave producer/consumer: compiler inserts lgkmcnt, no barrier)
        const short8 bf0 = *reinterpret_cast<const short8*>(&myhT[p * HSTRIDE + 8 * G]);
        const short8 bf1 = *reinterpret_cast<const short8*>(&myhT[p * HSTRIDE + 32 + 8 * G]);

        #pragma unroll
        for (int mt = 0; mt < 4; ++mt) {
            f32x4 at = ut[mt];   // bias + U-projection via MFMA C-init
            f32x4 af = uh[mt];
            at = __builtin_amdgcn_mfma_f32_16x16x32_bf16(wt_frag[mt][0], bf0, at, 0, 0, 0);
            at = __builtin_amdgcn_mfma_f32_16x16x32_bf16(wt_frag[mt][1], bf1, at, 0, 0, 0);
            af = __builtin_amdgcn_mfma_f32_16x16x32_bf16(wh_frag[mt][0], bf0, af, 0, 0, 0);
            af = __builtin_amdgcn_mfma_f32_16x16x32_bf16(wh_frag[mt][1], bf1, af, 0, 0, 0);

            #pragma unroll
            for (int r = 0; r < 4; ++r) {
                const float traw = fminf(fmaxf(at[r], -50.0f), 50.0f);   // med3
                const float sp   = __logf(1.0f + __expf(traw));          // softplus
                const float tau  = fmaf(sp, 9.9f, 0.1f);                 // >= 0.1 always
                const float fa   = fminf(fmaxf(af[r], -30.0f), 30.0f);   // sigmoid sat. safe
                const float e    = __expf(-fa);
                const float se   = 1.0f + e;
                const float rr   = __builtin_amdgcn_rcpf(tau * se);      // one rcp for both
                const float rtau = rr * se;                              // = 1/tau
                const float sg   = rr * tau;                             // = sigmoid
                const float h    = hs[mt][r];
                hs[mt][r] = fmaf(0.125f, fmaf(-h, rtau, sg), h);         // Euler update
            }
        }
    }

    // ---- fp32 readout: v[o] = tanh(W_out[o]·h + b_out[o]) * 10 ----
    float p0 = 0.0f, p1 = 0.0f, p2 = 0.0f;
    #pragma unroll
    for (int mt = 0; mt < 4; ++mt) {
        #pragma unroll
        for (int r = 0; r < 4; ++r) {
            const int g = 16 * mt + 4 * G + r;
            const float h = hs[mt][r];
            p0 = fmaf(Wout[g],       h, p0);
            p1 = fmaf(Wout[64 + g],  h, p1);
            p2 = fmaf(Wout[128 + g], h, p2);
        }
    }
    p0 += __shfl_xor(p0, 16); p0 += __shfl_xor(p0, 32);
    p1 += __shfl_xor(p1, 16); p1 += __shfl_xor(p1, 32);
    p2 += __shfl_xor(p2, 16); p2 += __shfl_xor(p2, 32);

    if (G < 3) {
        float zz = (G == 0) ? p0 : (G == 1 ? p1 : p2);
        zz += bout[G];
        const float e2 = __expf(2.0f * zz);                       // tanh via exp
        const float t  = 1.0f - 2.0f * __builtin_amdgcn_rcpf(e2 + 1.0f);
        out[(b * 3 + G) * NPERB + n] = t * 10.0f;
    }
}

extern "C" void kernel_launch(void* const* d_in, const int* in_sizes, int n_in,
                              void* d_out, int out_size, void* d_ws, size_t ws_size,
                              hipStream_t stream) {
    const float* coords = (const float*)d_in[0];
    const float* Wh     = (const float*)d_in[1];
    const float* Uh     = (const float*)d_in[2];
    const float* bh     = (const float*)d_in[3];
    const float* Wtau   = (const float*)d_in[4];
    const float* Utau   = (const float*)d_in[5];
    const float* btau   = (const float*)d_in[6];
    const float* Wout   = (const float*)d_in[7];
    const float* bout   = (const float*)d_in[8];
    float* out = (float*)d_out;

    // 221184 points / (4 waves * 16 points) = 3456 blocks of 256 threads
    liquid_ode_kernel<<<dim3(NTOTAL / 64), dim3(256), 0, stream>>>(
        coords, Wh, Uh, bh, Wtau, Utau, btau, Wout, bout, out);
}